// Round 10
// baseline (1080.747 us; speedup 1.0000x reference)
//
#include <hip/hip_runtime.h>
#include <math.h>

#define EPSF 1e-8f
#define MARGIN 4e-3f

constexpr int Bn = 16, Cc = 256, HW = 1024, Ee = 512, Vv = 8192;
constexpr int Mm = Bn * HW; // 16384 pixels

// d_out float offsets: z | z_q | decoder_input | tokens(float)
constexpr long O_Z   = 0;
constexpr long O_ZQ  = 8388608;
constexpr long O_DEC = 16777216;
constexpr long O_TOK = 25165824;

typedef __attribute__((ext_vector_type(8))) short s16x8;
typedef __attribute__((ext_vector_type(4))) short s16x4;
typedef __attribute__((ext_vector_type(8))) _Float16 f16x8;
typedef __attribute__((ext_vector_type(4))) float f32x4;

__device__ __forceinline__ unsigned short f2h(float x) {
    _Float16 h = (_Float16)x;
    return __builtin_bit_cast(unsigned short, h);
}
__device__ __forceinline__ float h2f(unsigned short b) {
    return (float)__builtin_bit_cast(_Float16, b);
}

// ---------------- k_prep: wT transpose + embedding norms/fp16 B + cnt zero ----------------

__global__ void k_prep(const float* __restrict__ w, float* __restrict__ wT,
                       const float* __restrict__ emb, float* __restrict__ en_inv,
                       float* __restrict__ en_norm, unsigned short* __restrict__ Bhi,
                       int* __restrict__ cnt) {
    int b = blockIdx.x, t = threadIdx.x;
    int v = b * 4 + (t >> 6);
    int lane = t & 63;
    const float* row = emb + (long)v * Ee + lane * 8;
    float4 d0 = *(const float4*)row;
    float4 d1 = *(const float4*)(row + 4);
    float s = 0.f;
    s = fmaf(d0.x, d0.x, s); s = fmaf(d0.y, d0.y, s);
    s = fmaf(d0.z, d0.z, s); s = fmaf(d0.w, d0.w, s);
    s = fmaf(d1.x, d1.x, s); s = fmaf(d1.y, d1.y, s);
    s = fmaf(d1.z, d1.z, s); s = fmaf(d1.w, d1.w, s);
#pragma unroll
    for (int off = 32; off; off >>= 1) s += __shfl_xor(s, off);
    float n = sqrtf(s);
    float inv = 1.0f / (EPSF + n);
    if (lane == 0) { en_norm[v] = EPSF + n; en_inv[v] = inv; }
    s16x8 h;
    h[0] = (short)f2h(d0.x * inv); h[1] = (short)f2h(d0.y * inv);
    h[2] = (short)f2h(d0.z * inv); h[3] = (short)f2h(d0.w * inv);
    h[4] = (short)f2h(d1.x * inv); h[5] = (short)f2h(d1.y * inv);
    h[6] = (short)f2h(d1.z * inv); h[7] = (short)f2h(d1.w * inv);
    *(s16x8*)(Bhi + (long)v * Ee + lane * 8) = h;
    if (b < 512) {
        int gid = b * 256 + t;
        int c = gid >> 9, e = gid & 511;
        wT[gid] = w[e * Cc + c];
    } else if (b < 576) {
        cnt[(b - 512) * 256 + t] = 0;
    }
}

// ---------------- GEMM1: z + fp16 hi/lo of UNNORMALIZED z ([p][e]) + sumsq partials ----------------

__global__ __launch_bounds__(256) void k_gemm1(const float* __restrict__ x,
                                               const float* __restrict__ wT,
                                               const float* __restrict__ bias,
                                               float* __restrict__ z,
                                               unsigned short* __restrict__ Ahi,
                                               unsigned short* __restrict__ Alo,
                                               float* __restrict__ sumsq_part) {
    __shared__ float As[32][64];
    __shared__ float Bs[32][64];
    int m0 = blockIdx.x * 64;                 // pixel tile
    int b = m0 >> 10, hw0 = m0 & 1023;
    int e0 = blockIdx.y * 64;
    int t = threadIdx.x;
    int mi = t >> 4, ni = t & 15;
    float acc[4][4] = {};
    for (int c0 = 0; c0 < Cc; c0 += 32) {
#pragma unroll
        for (int q = 0; q < 2; ++q) {
            int f = t + 256 * q;
            int kk = f >> 4, m4 = (f & 15) * 4;
            *(float4*)&As[kk][m4] = *(const float4*)(x + ((long)(b * Cc + c0 + kk)) * HW + hw0 + m4);
            *(float4*)&Bs[kk][m4] = *(const float4*)(wT + (long)(c0 + kk) * Ee + e0 + m4);
        }
        __syncthreads();
#pragma unroll
        for (int kk = 0; kk < 32; ++kk) {
            float4 a = *(float4*)&As[kk][mi * 4];
            float4 bv = *(float4*)&Bs[kk][ni * 4];
            float av[4] = {a.x, a.y, a.z, a.w};
            float bb[4] = {bv.x, bv.y, bv.z, bv.w};
#pragma unroll
            for (int r = 0; r < 4; ++r)
#pragma unroll
                for (int c = 0; c < 4; ++c) acc[r][c] = fmaf(av[r], bb[c], acc[r][c]);
        }
        __syncthreads();
    }
    float ov[4][4];
#pragma unroll
    for (int c = 0; c < 4; ++c) {
        int e = e0 + ni * 4 + c;
        float be = bias[e];
#pragma unroll
        for (int r = 0; r < 4; ++r) ov[r][c] = acc[r][c] + be;
        float4 o = make_float4(ov[0][c], ov[1][c], ov[2][c], ov[3][c]);
        *(float4*)(z + ((long)(b * Ee + e)) * HW + hw0 + mi * 4) = o;
    }
    float sq[4] = {0.f, 0.f, 0.f, 0.f};
#pragma unroll
    for (int c = 0; c < 4; ++c) {   // same accumulation order as previous rounds
        sq[0] = fmaf(ov[0][c], ov[0][c], sq[0]);
        sq[1] = fmaf(ov[1][c], ov[1][c], sq[1]);
        sq[2] = fmaf(ov[2][c], ov[2][c], sq[2]);
        sq[3] = fmaf(ov[3][c], ov[3][c], sq[3]);
    }
#pragma unroll
    for (int r = 0; r < 4; ++r) {
        s16x4 h, lo;
#pragma unroll
        for (int c = 0; c < 4; ++c) {
            unsigned short hh = f2h(ov[r][c]);
            h[c]  = (short)hh;
            lo[c] = (short)f2h(ov[r][c] - h2f(hh));
        }
        long off = (long)(m0 + mi * 4 + r) * Ee + e0 + ni * 4;
        *(s16x4*)(Ahi + off) = h;
        *(s16x4*)(Alo + off) = lo;
    }
#pragma unroll
    for (int r = 0; r < 4; ++r)
#pragma unroll
        for (int off = 1; off < 16; off <<= 1) sq[r] += __shfl_xor(sq[r], off);
    if (ni == 0) {
#pragma unroll
        for (int r = 0; r < 4; ++r)
            sumsq_part[(long)(m0 + mi * 4 + r) * 8 + blockIdx.y] = sq[r];
    }
}

// ---------------- k_norm: fold 8 sumsq partials -> norm / inv_zn ----------------

__global__ void k_norm(const float* __restrict__ sumsq_part, float* __restrict__ norm,
                       float* __restrict__ inv_zn) {
    int p = blockIdx.x * 256 + threadIdx.x;
    const float* sp = sumsq_part + (long)p * 8;
    float s = ((sp[0] + sp[1]) + (sp[2] + sp[3])) + ((sp[4] + sp[5]) + (sp[6] + sp[7]));
    float nv = EPSF + sqrtf(s);
    norm[p] = nv;
    inv_zn[p] = 1.0f / nv;
}

// ---------------- fp16 MFMA sims (R7 core) with 4 v-tiles per block ----------------
// 2048 blocks = 128 m-tiles x 16 v-quads, 256 thr = 4 waves (2x2).
// Per block: kt = 0..31 (4 v-tiles x 8 K-steps). Single 32KB LDS buffer,
// global_load_lds staging, 2 barriers/step (R7, measured best). The DMA
// pipeline never refills at v-tile boundaries: next tile's kt=0 DMAs are
// issued before the epilogue and drain underneath it. A side = UNNORMALIZED
// z fp16 (per-row scale drops out of argmax); margin scaled by norm[p].

__global__ __launch_bounds__(256, 4) void k_sims(const unsigned short* __restrict__ Ahi,
                                                 const unsigned short* __restrict__ Bhi,
                                                 const float* __restrict__ norm,
                                                 float* __restrict__ part_v,
                                                 int* __restrict__ part_i,
                                                 float2* __restrict__ extras,
                                                 int* __restrict__ cnt) {
    __shared__ short As[8192];   // [row*64 + slot*8 + e]  16KB
    __shared__ short Bs[8192];
    __shared__ float red_v[2][2][64];
    __shared__ int   red_i[2][2][64];
    __shared__ float red_m[2][64];
    __shared__ int   red_wi[2][64];

    int t = threadIdx.x;
    int wg = blockIdx.x;
    int xcd = wg & 7, r = wg >> 3;
    int bx = xcd * 16 + (r & 15);     // m-tile 0..127 (XCD-chunked: A L2-hot)
    int quad = r >> 4;                // v-quad 0..15 (512 v each)
    long m0 = (long)bx * 128;
    long nq0 = (long)quad * 512;

    int wid = t >> 6, l = t & 63;
    int wr = wid >> 1, wc = wid & 1;
    int l15 = l & 15, lg = l >> 4;

    auto stage = [&](const unsigned short* gbase, short* region, long row0, int k0) {
#pragma unroll
        for (int j = 0; j < 4; ++j) {
            int i = j * 256 + t;               // slot 0..1023
            int rr = i >> 3, s = i & 7;
            int sp = s ^ (rr & 7);             // pre-swizzled global source
            const unsigned short* gp = gbase + (row0 + rr) * Ee + k0 + sp * 8;
            short* lp = region + (long)(j * 256 + (t & ~63)) * 8;  // wave-uniform
            __builtin_amdgcn_global_load_lds(
                (const __attribute__((address_space(1))) unsigned int*)gp,
                (__attribute__((address_space(3))) unsigned int*)lp, 16, 0, 0);
        }
    };

    f32x4 acc[4][4];
#pragma unroll
    for (int i = 0; i < 4; ++i)
#pragma unroll
        for (int j = 0; j < 4; ++j) acc[i][j] = (f32x4){0.f, 0.f, 0.f, 0.f};

    stage(Ahi, As, m0, 0);
    stage(Bhi, Bs, nq0, 0);

    for (int kt = 0; kt < 32; ++kt) {
        __syncthreads();   // vmcnt(0)+barrier: tile kt landed for all waves
        s16x8 af[4][2], bf[4][2];
#pragma unroll
        for (int mt = 0; mt < 4; ++mt)
#pragma unroll
            for (int kk = 0; kk < 2; ++kk) {
                int row = wr * 64 + mt * 16 + l15;
                int g = kk * 4 + lg;
                af[mt][kk] = *(const s16x8*)&As[row * 64 + ((g ^ (row & 7)) * 8)];
                int nrow = wc * 64 + mt * 16 + l15;
                bf[mt][kk] = *(const s16x8*)&Bs[nrow * 64 + ((g ^ (nrow & 7)) * 8)];
            }
        __syncthreads();   // all waves' reads complete
        if (kt < 31) {
            int nk = kt + 1;
            stage(Ahi, As, m0, (nk & 7) * 64);            // DMAs fly under MFMAs
            stage(Bhi, Bs, nq0 + (long)(nk >> 3) * 128, (nk & 7) * 64);
        }
#pragma unroll
        for (int kk = 0; kk < 2; ++kk)
#pragma unroll
            for (int mt = 0; mt < 4; ++mt)
#pragma unroll
                for (int nt = 0; nt < 4; ++nt)
                    acc[mt][nt] = __builtin_amdgcn_mfma_f32_16x16x32_f16(
                        __builtin_bit_cast(f16x8, af[mt][kk]),
                        __builtin_bit_cast(f16x8, bf[nt][kk]), acc[mt][nt], 0, 0, 0);

        if ((kt & 7) == 7) {
            // ---- per-v-tile epilogue (C/D: col = l&15, row = (l>>4)*4 + reg) ----
            int byv = quad * 4 + (kt >> 3);   // v-tile 0..63
            long n0 = (long)byv * 128;
#pragma unroll
            for (int mt = 0; mt < 4; ++mt)
#pragma unroll
                for (int rg = 0; rg < 4; ++rg) {
                    float best = -3e38f; int bi = 0x7FFFFFFF;
#pragma unroll
                    for (int nt = 0; nt < 4; ++nt) {
                        float val = acc[mt][nt][rg];
                        int idx = (int)n0 + wc * 64 + nt * 16 + l15;
                        if (val > best) { best = val; bi = idx; }
                    }
#pragma unroll
                    for (int off = 1; off < 16; off <<= 1) {
                        float ov = __shfl_xor(best, off);
                        int oi = __shfl_xor(bi, off);
                        if (ov > best || (ov == best && oi < bi)) { best = ov; bi = oi; }
                    }
                    if (l15 == 0) {
                        int rloc = mt * 16 + lg * 4 + rg;
                        red_v[wr][wc][rloc] = best;
                        red_i[wr][wc][rloc] = bi;
                    }
                }
            __syncthreads();
            if (t < 128) {
                int wr_ = t >> 6, rloc = t & 63;
                float va = red_v[wr_][0][rloc]; int ia = red_i[wr_][0][rloc];
                float vb = red_v[wr_][1][rloc]; int ib = red_i[wr_][1][rloc];
                if (vb > va || (vb == va && ib < ia)) { va = vb; ia = ib; }
                long m = m0 + wr_ * 64 + rloc;
                part_v[m * 64 + byv] = va;
                part_i[m * 64 + byv] = ia;
                red_m[wr_][rloc] = va;
                red_wi[wr_][rloc] = ia;
            }
            __syncthreads();
            // extras: every non-winner col within MARGIN*norm of the stripe max
#pragma unroll
            for (int mt = 0; mt < 4; ++mt)
#pragma unroll
                for (int rg = 0; rg < 4; ++rg) {
                    int rloc = mt * 16 + lg * 4 + rg;
                    float bm = red_m[wr][rloc];
                    int wi_ = red_wi[wr][rloc];
                    long p = m0 + wr * 64 + rloc;
                    float thr = bm - MARGIN * norm[p];
#pragma unroll
                    for (int nt = 0; nt < 4; ++nt) {
                        float val = acc[mt][nt][rg];
                        int idx = (int)n0 + wc * 64 + nt * 16 + l15;
                        if (val >= thr && idx != wi_) {
                            int slot = atomicAdd(&cnt[p], 1);
                            if (slot < 64) extras[p * 64 + slot] = make_float2(val, __int_as_float(idx));
                        }
                    }
                }
            // reset acc for next v-tile
#pragma unroll
            for (int i = 0; i < 4; ++i)
#pragma unroll
                for (int j = 0; j < 4; ++j) acc[i][j] = (f32x4){0.f, 0.f, 0.f, 0.f};
        }
    }
}

// ---------------- k_pick: global m1, candidate set, exact f32 rescore ----------------

__global__ __launch_bounds__(256) void k_pick(const float* __restrict__ part_v,
                                              const int* __restrict__ part_i,
                                              const float2* __restrict__ extras,
                                              const int* __restrict__ cnt,
                                              const unsigned short* __restrict__ Ahi,
                                              const unsigned short* __restrict__ Alo,
                                              const float* __restrict__ emb,
                                              const float* __restrict__ en_inv,
                                              const float* __restrict__ norm,
                                              int* __restrict__ tok_i,
                                              float* __restrict__ tok_f) {
    int p = blockIdx.x * 4 + (threadIdx.x >> 6);
    int lane = threadIdx.x & 63;
    float wv = part_v[(long)p * 64 + lane];
    int wi = part_i[(long)p * 64 + lane];
    float m1 = wv;
#pragma unroll
    for (int off = 1; off < 64; off <<= 1) {
        float ov = __shfl_xor(m1, off);
        if (ov > m1) m1 = ov;
    }
    float thr = m1 - MARGIN * norm[p];
    int n = cnt[p]; if (n > 64) n = 64;
    float ev = -3e38f; int ei = 0;
    if (lane < n) {
        float2 e2 = extras[(long)p * 64 + lane];
        ev = e2.x; ei = __float_as_int(e2.y);
    }
    unsigned long long mw = __ballot(wv >= thr);
    unsigned long long me = __ballot(ev >= thr);
    // reconstruct this pixel's (unnormalized) z slice; per-pixel scale cancels
    s16x8 ah = *(const s16x8*)(Ahi + (long)p * Ee + lane * 8);
    s16x8 al = *(const s16x8*)(Alo + (long)p * Ee + lane * 8);
    float a[8];
#pragma unroll
    for (int j = 0; j < 8; ++j)
        a[j] = h2f((unsigned short)ah[j]) + h2f((unsigned short)al[j]);

    float best = -3e38f; int bi = 0x7FFFFFFF;
    auto rescore = [&](int v) {
        const float* er = emb + (long)v * Ee + lane * 8;
        float4 b0 = *(const float4*)er;
        float4 b1 = *(const float4*)(er + 4);
        float s = 0.f;
        s = fmaf(a[0], b0.x, s); s = fmaf(a[1], b0.y, s);
        s = fmaf(a[2], b0.z, s); s = fmaf(a[3], b0.w, s);
        s = fmaf(a[4], b1.x, s); s = fmaf(a[5], b1.y, s);
        s = fmaf(a[6], b1.z, s); s = fmaf(a[7], b1.w, s);
#pragma unroll
        for (int off = 1; off < 64; off <<= 1) s += __shfl_xor(s, off);
        s *= en_inv[v];
        if (s > best || (s == best && v < bi)) { best = s; bi = v; }
    };
    while (mw) {
        int b = __ffsll(mw) - 1; mw &= mw - 1;
        rescore(__shfl(wi, b));
    }
    while (me) {
        int b = __ffsll(me) - 1; me &= me - 1;
        rescore(__shfl(ei, b));
    }
    if (lane == 0) { tok_i[p] = bi; tok_f[p] = (float)bi; }
}

// ---------------- finalize: z_q gather + straight-through blend ----------------

__global__ void k_final(const float* __restrict__ z, const float* __restrict__ emb,
                        const int* __restrict__ tok, const float* __restrict__ inv_zn,
                        const float* __restrict__ en_inv, const float* __restrict__ en_norm,
                        float* __restrict__ zq, float* __restrict__ dec) {
    long gid = (long)blockIdx.x * 256 + threadIdx.x;   // 0..8388607
    int hw = (int)(gid & 1023);
    int b  = (int)(gid >> 19);
    int p  = (b << 10) | hw;
    int e  = (int)((gid >> 10) & 511);
    int tk = tok[p];
    float zqv = emb[(long)tk * Ee + e];
    float nq  = en_norm[tk];
    float nzq = zqv * en_inv[tk];
    float zv  = z[gid];
    float nz  = zv * inv_zn[p];
    zq[gid]  = zqv;
    dec[gid] = (nz + (nzq - nz)) * nq;
}

// ---------------- launch ----------------

extern "C" void kernel_launch(void* const* d_in, const int* in_sizes, int n_in,
                              void* d_out, int out_size, void* d_ws, size_t ws_size,
                              hipStream_t stream) {
    const float* x     = (const float*)d_in[0];
    const float* w_pre = (const float*)d_in[1];
    const float* b_pre = (const float*)d_in[2];
    const float* emb   = (const float*)d_in[3];

    float* out  = (float*)d_out;
    float* z    = out + O_Z;
    float* zq   = out + O_ZQ;
    float* dec  = out + O_DEC;
    float* tokf = out + O_TOK;

    // zq region (32MB): Ahi | Alo  fp16 [16384][512] each (dead until k_final)
    unsigned short* Ahi = (unsigned short*)zq;
    unsigned short* Alo = Ahi + (long)Mm * Ee;
    // dec region (8M floats): Bhi(2M) | part_v(1M) | part_i(1M) | extras(2M) | cnt | sumsq
    unsigned short* Bhi = (unsigned short*)dec;
    float*  part_v = dec + 2 * 1024 * 1024;
    int*    part_i = (int*)(dec + 3 * 1024 * 1024);
    float2* extras = (float2*)(dec + 4 * 1024 * 1024);
    int*    cnt    = (int*)(dec + 6 * 1024 * 1024);
    float*  sumsq_part = dec + 6 * 1024 * 1024 + 32768;   // 16384*8 floats

    float* ws      = (float*)d_ws;
    float* wT      = ws;                // 131072
    float* en_inv  = wT + 131072;       // 8192
    float* en_norm = en_inv + 8192;     // 8192
    float* inv_zn  = en_norm + 8192;    // 16384
    int*   tok_i   = (int*)(inv_zn + 16384); // 16384
    float* norm    = (float*)(tok_i + 16384); // 16384

    k_prep<<<2048, 256, 0, stream>>>(w_pre, wT, emb, en_inv, en_norm, Bhi, cnt);
    dim3 g1(Mm / 64, Ee / 64);
    k_gemm1<<<g1, 256, 0, stream>>>(x, wT, b_pre, z, Ahi, Alo, sumsq_part);
    k_norm<<<Mm / 256, 256, 0, stream>>>(sumsq_part, norm, inv_zn);
    k_sims<<<2048, 256, 0, stream>>>(Ahi, Bhi, norm, part_v, part_i, extras, cnt);
    k_pick<<<Mm / 4, 256, 0, stream>>>(part_v, part_i, extras, cnt, Ahi, Alo, emb,
                                       en_inv, norm, tok_i, tokf);
    k_final<<<(int)(8388608 / 256), 256, 0, stream>>>(z, emb, tok_i, inv_zn, en_inv, en_norm, zq, dec);
}

// Round 11
// 442.586 us; speedup vs baseline: 2.4419x; 2.4419x over previous
//
#include <hip/hip_runtime.h>
#include <math.h>

#define EPSF 1e-8f
#define MARGIN 4e-3f

constexpr int Bn = 16, Cc = 256, HW = 1024, Ee = 512, Vv = 8192;
constexpr int Mm = Bn * HW; // 16384 pixels

// d_out float offsets: z | z_q | decoder_input | tokens(float)
constexpr long O_Z   = 0;
constexpr long O_ZQ  = 8388608;
constexpr long O_DEC = 16777216;
constexpr long O_TOK = 25165824;

typedef __attribute__((ext_vector_type(8))) short s16x8;
typedef __attribute__((ext_vector_type(4))) short s16x4;
typedef __attribute__((ext_vector_type(8))) _Float16 f16x8;
typedef __attribute__((ext_vector_type(4))) float f32x4;

__device__ __forceinline__ unsigned short f2h(float x) {
    _Float16 h = (_Float16)x;
    return __builtin_bit_cast(unsigned short, h);
}
__device__ __forceinline__ float h2f(unsigned short b) {
    return (float)__builtin_bit_cast(_Float16, b);
}

// ---------------- k_prep: wT transpose + embedding norms/fp16 B + cnt zero ----------------

__global__ void k_prep(const float* __restrict__ w, float* __restrict__ wT,
                       const float* __restrict__ emb, float* __restrict__ en_inv,
                       float* __restrict__ en_norm, unsigned short* __restrict__ Bhi,
                       int* __restrict__ cnt) {
    int b = blockIdx.x, t = threadIdx.x;
    int v = b * 4 + (t >> 6);
    int lane = t & 63;
    const float* row = emb + (long)v * Ee + lane * 8;
    float4 d0 = *(const float4*)row;
    float4 d1 = *(const float4*)(row + 4);
    float s = 0.f;
    s = fmaf(d0.x, d0.x, s); s = fmaf(d0.y, d0.y, s);
    s = fmaf(d0.z, d0.z, s); s = fmaf(d0.w, d0.w, s);
    s = fmaf(d1.x, d1.x, s); s = fmaf(d1.y, d1.y, s);
    s = fmaf(d1.z, d1.z, s); s = fmaf(d1.w, d1.w, s);
#pragma unroll
    for (int off = 32; off; off >>= 1) s += __shfl_xor(s, off);
    float n = sqrtf(s);
    float inv = 1.0f / (EPSF + n);
    if (lane == 0) { en_norm[v] = EPSF + n; en_inv[v] = inv; }
    s16x8 h;
    h[0] = (short)f2h(d0.x * inv); h[1] = (short)f2h(d0.y * inv);
    h[2] = (short)f2h(d0.z * inv); h[3] = (short)f2h(d0.w * inv);
    h[4] = (short)f2h(d1.x * inv); h[5] = (short)f2h(d1.y * inv);
    h[6] = (short)f2h(d1.z * inv); h[7] = (short)f2h(d1.w * inv);
    *(s16x8*)(Bhi + (long)v * Ee + lane * 8) = h;
    if (b < 512) {
        int gid = b * 256 + t;
        int c = gid >> 9, e = gid & 511;
        wT[gid] = w[e * Cc + c];
    } else if (b < 576) {
        cnt[(b - 512) * 256 + t] = 0;
    }
}

// ---------------- GEMM1 (128x128 tile): z + fp16 hi/lo of UNNORMALIZED z + sumsq ----------------
// grid (128, 4): x re-read 4x (L3-hot) instead of 8x; 8x8 micro-tile:
// 64 FMA per 4 ds_read_b128 (was 16 per 2).

__global__ __launch_bounds__(256) void k_gemm1(const float* __restrict__ x,
                                               const float* __restrict__ wT,
                                               const float* __restrict__ bias,
                                               float* __restrict__ z,
                                               unsigned short* __restrict__ Ahi,
                                               unsigned short* __restrict__ Alo,
                                               float* __restrict__ sumsq_part) {
    __shared__ float As[32][128];   // x tile  [c][p]  16KB
    __shared__ float Bs[32][128];   // wT tile [c][e]  16KB
    int m0 = blockIdx.x * 128;                // pixel tile
    int b = m0 >> 10, hw0 = m0 & 1023;
    int e0 = blockIdx.y * 128;
    int t = threadIdx.x;
    int mi = t >> 4, ni = t & 15;             // 8 pixels x 8 e per thread
    float acc[8][8] = {};
    for (int c0 = 0; c0 < Cc; c0 += 32) {
#pragma unroll
        for (int q = 0; q < 4; ++q) {
            int f = t + 256 * q;              // 0..1023
            int kk = f >> 5, p4 = (f & 31) * 4;
            *(float4*)&As[kk][p4] = *(const float4*)(x + ((long)(b * Cc + c0 + kk)) * HW + hw0 + p4);
            *(float4*)&Bs[kk][p4] = *(const float4*)(wT + (long)(c0 + kk) * Ee + e0 + p4);
        }
        __syncthreads();
#pragma unroll
        for (int kk = 0; kk < 32; ++kk) {
            float av[8], bv[8];
            *(float4*)&av[0] = *(float4*)&As[kk][mi * 8];
            *(float4*)&av[4] = *(float4*)&As[kk][mi * 8 + 4];
            *(float4*)&bv[0] = *(float4*)&Bs[kk][ni * 8];
            *(float4*)&bv[4] = *(float4*)&Bs[kk][ni * 8 + 4];
#pragma unroll
            for (int r = 0; r < 8; ++r)
#pragma unroll
                for (int c = 0; c < 8; ++c) acc[r][c] = fmaf(av[r], bv[c], acc[r][c]);
        }
        __syncthreads();
    }
    float ov[8][8];
#pragma unroll
    for (int c = 0; c < 8; ++c) {
        int e = e0 + ni * 8 + c;
        float be = bias[e];
#pragma unroll
        for (int r = 0; r < 8; ++r) ov[r][c] = acc[r][c] + be;
        float4 o0 = make_float4(ov[0][c], ov[1][c], ov[2][c], ov[3][c]);
        float4 o1 = make_float4(ov[4][c], ov[5][c], ov[6][c], ov[7][c]);
        float* zp = z + ((long)(b * Ee + e)) * HW + hw0 + mi * 8;
        *(float4*)zp = o0;
        *(float4*)(zp + 4) = o1;
    }
    float sq[8];
#pragma unroll
    for (int r = 0; r < 8; ++r) {
        s16x8 h, lo;
        float s = 0.f;
#pragma unroll
        for (int c = 0; c < 8; ++c) {
            unsigned short hh = f2h(ov[r][c]);
            h[c]  = (short)hh;
            lo[c] = (short)f2h(ov[r][c] - h2f(hh));
            s = fmaf(ov[r][c], ov[r][c], s);
        }
        sq[r] = s;
        long off = (long)(m0 + mi * 8 + r) * Ee + e0 + ni * 8;
        *(s16x8*)(Ahi + off) = h;
        *(s16x8*)(Alo + off) = lo;
    }
#pragma unroll
    for (int r = 0; r < 8; ++r)
#pragma unroll
        for (int off = 1; off < 16; off <<= 1) sq[r] += __shfl_xor(sq[r], off);
    if (ni == 0) {
#pragma unroll
        for (int r = 0; r < 8; ++r)
            sumsq_part[(long)(m0 + mi * 8 + r) * 4 + blockIdx.y] = sq[r];
    }
}

// ---------------- k_norm: fold 4 sumsq partials -> norm / inv_zn ----------------

__global__ void k_norm(const float* __restrict__ sumsq_part, float* __restrict__ norm,
                       float* __restrict__ inv_zn) {
    int p = blockIdx.x * 256 + threadIdx.x;
    const float* sp = sumsq_part + (long)p * 4;
    float s = (sp[0] + sp[1]) + (sp[2] + sp[3]);
    float nv = EPSF + sqrtf(s);
    norm[p] = nv;
    inv_zn[p] = 1.0f / nv;
}

// ---------------- fp16 MFMA sims: R7 structure verbatim, norm-scaled margin ----------------
// 8192 blocks (128 m x 64 v), 256 thr = 4 waves (2x2), 128x128 tile, K=512.
// Single 32KB LDS buffer, global_load_lds staging, 2 barriers/K-step.
// R10 lesson: do NOT perturb this grid mapping — the 16 co-resident m-tiles
// per XCD sharing one B-tile is what keeps FETCH at 42MB.

__global__ __launch_bounds__(256, 4) void k_sims(const unsigned short* __restrict__ Ahi,
                                                 const unsigned short* __restrict__ Bhi,
                                                 const float* __restrict__ norm,
                                                 float* __restrict__ part_v,
                                                 int* __restrict__ part_i,
                                                 float2* __restrict__ extras,
                                                 int* __restrict__ cnt) {
    __shared__ short As[8192];   // [row*64 + slot*8 + e]  16KB
    __shared__ short Bs[8192];
    __shared__ float red_v[2][2][64];
    __shared__ int   red_i[2][2][64];
    __shared__ float red_m[2][64];
    __shared__ int   red_wi[2][64];

    int t = threadIdx.x;
    int wg = blockIdx.x;
    int xcd = wg & 7, r = wg >> 3;
    int bx = xcd * 16 + (r & 15);     // 0..127  (m-tile), XCD-chunked
    int by = r >> 4;                  // 0..63   (v-tile)
    long m0 = (long)bx * 128, n0 = (long)by * 128;

    int wid = t >> 6, l = t & 63;
    int wr = wid >> 1, wc = wid & 1;
    int l15 = l & 15, lg = l >> 4;

    auto stage = [&](const unsigned short* gbase, short* region, long row0, int k0) {
#pragma unroll
        for (int j = 0; j < 4; ++j) {
            int i = j * 256 + t;               // slot 0..1023
            int rr = i >> 3, s = i & 7;
            int sp = s ^ (rr & 7);             // pre-swizzled global source
            const unsigned short* gp = gbase + (row0 + rr) * Ee + k0 + sp * 8;
            short* lp = region + (long)(j * 256 + (t & ~63)) * 8;  // wave-uniform
            __builtin_amdgcn_global_load_lds(
                (const __attribute__((address_space(1))) unsigned int*)gp,
                (__attribute__((address_space(3))) unsigned int*)lp, 16, 0, 0);
        }
    };

    f32x4 acc[4][4];
#pragma unroll
    for (int i = 0; i < 4; ++i)
#pragma unroll
        for (int j = 0; j < 4; ++j) acc[i][j] = (f32x4){0.f, 0.f, 0.f, 0.f};

    stage(Ahi, As, m0, 0);
    stage(Bhi, Bs, n0, 0);

    for (int kt = 0; kt < 8; ++kt) {
        __syncthreads();   // vmcnt(0)+barrier: tile kt landed for all waves
        s16x8 af[4][2], bf[4][2];
#pragma unroll
        for (int mt = 0; mt < 4; ++mt)
#pragma unroll
            for (int kk = 0; kk < 2; ++kk) {
                int row = wr * 64 + mt * 16 + l15;
                int g = kk * 4 + lg;
                af[mt][kk] = *(const s16x8*)&As[row * 64 + ((g ^ (row & 7)) * 8)];
                int nrow = wc * 64 + mt * 16 + l15;
                bf[mt][kk] = *(const s16x8*)&Bs[nrow * 64 + ((g ^ (nrow & 7)) * 8)];
            }
        __syncthreads();   // all waves' reads complete
        if (kt < 7) {
            stage(Ahi, As, m0, (kt + 1) * 64);   // DMAs fly under the MFMAs
            stage(Bhi, Bs, n0, (kt + 1) * 64);
        }
#pragma unroll
        for (int kk = 0; kk < 2; ++kk)
#pragma unroll
            for (int mt = 0; mt < 4; ++mt)
#pragma unroll
                for (int nt = 0; nt < 4; ++nt)
                    acc[mt][nt] = __builtin_amdgcn_mfma_f32_16x16x32_f16(
                        __builtin_bit_cast(f16x8, af[mt][kk]),
                        __builtin_bit_cast(f16x8, bf[nt][kk]), acc[mt][nt], 0, 0, 0);
    }

    // ---- winner epilogue (C/D: col = l&15, row = (l>>4)*4 + reg) ----
#pragma unroll
    for (int mt = 0; mt < 4; ++mt)
#pragma unroll
        for (int rg = 0; rg < 4; ++rg) {
            float best = -3e38f; int bi = 0x7FFFFFFF;
#pragma unroll
            for (int nt = 0; nt < 4; ++nt) {
                float val = acc[mt][nt][rg];
                int idx = (int)n0 + wc * 64 + nt * 16 + l15;
                if (val > best) { best = val; bi = idx; }
            }
#pragma unroll
            for (int off = 1; off < 16; off <<= 1) {
                float ov = __shfl_xor(best, off);
                int oi = __shfl_xor(bi, off);
                if (ov > best || (ov == best && oi < bi)) { best = ov; bi = oi; }
            }
            if (l15 == 0) {
                int rloc = mt * 16 + lg * 4 + rg;
                red_v[wr][wc][rloc] = best;
                red_i[wr][wc][rloc] = bi;
            }
        }
    __syncthreads();
    if (t < 128) {
        int wr_ = t >> 6, rloc = t & 63;
        float va = red_v[wr_][0][rloc]; int ia = red_i[wr_][0][rloc];
        float vb = red_v[wr_][1][rloc]; int ib = red_i[wr_][1][rloc];
        if (vb > va || (vb == va && ib < ia)) { va = vb; ia = ib; }
        long m = m0 + wr_ * 64 + rloc;
        part_v[m * 64 + by] = va;
        part_i[m * 64 + by] = ia;
        red_m[wr_][rloc] = va;
        red_wi[wr_][rloc] = ia;
    }
    __syncthreads();
    // ---- extras: every non-winner col within MARGIN*norm of the stripe max ----
#pragma unroll
    for (int mt = 0; mt < 4; ++mt)
#pragma unroll
        for (int rg = 0; rg < 4; ++rg) {
            int rloc = mt * 16 + lg * 4 + rg;
            float bm = red_m[wr][rloc];
            int wi_ = red_wi[wr][rloc];
            long p = m0 + wr * 64 + rloc;
            float thr = bm - MARGIN * norm[p];
#pragma unroll
            for (int nt = 0; nt < 4; ++nt) {
                float val = acc[mt][nt][rg];
                int idx = (int)n0 + wc * 64 + nt * 16 + l15;
                if (val >= thr && idx != wi_) {
                    int slot = atomicAdd(&cnt[p], 1);
                    if (slot < 64) extras[p * 64 + slot] = make_float2(val, __int_as_float(idx));
                }
            }
        }
}

// ---------------- k_pick: global m1, candidate set, exact f32 rescore ----------------

__global__ __launch_bounds__(256) void k_pick(const float* __restrict__ part_v,
                                              const int* __restrict__ part_i,
                                              const float2* __restrict__ extras,
                                              const int* __restrict__ cnt,
                                              const unsigned short* __restrict__ Ahi,
                                              const unsigned short* __restrict__ Alo,
                                              const float* __restrict__ emb,
                                              const float* __restrict__ en_inv,
                                              const float* __restrict__ norm,
                                              int* __restrict__ tok_i,
                                              float* __restrict__ tok_f) {
    int p = blockIdx.x * 4 + (threadIdx.x >> 6);
    int lane = threadIdx.x & 63;
    float wv = part_v[(long)p * 64 + lane];
    int wi = part_i[(long)p * 64 + lane];
    float m1 = wv;
#pragma unroll
    for (int off = 1; off < 64; off <<= 1) {
        float ov = __shfl_xor(m1, off);
        if (ov > m1) m1 = ov;
    }
    float thr = m1 - MARGIN * norm[p];
    int n = cnt[p]; if (n > 64) n = 64;
    float ev = -3e38f; int ei = 0;
    if (lane < n) {
        float2 e2 = extras[(long)p * 64 + lane];
        ev = e2.x; ei = __float_as_int(e2.y);
    }
    unsigned long long mw = __ballot(wv >= thr);
    unsigned long long me = __ballot(ev >= thr);
    // reconstruct this pixel's (unnormalized) z slice; per-pixel scale cancels
    s16x8 ah = *(const s16x8*)(Ahi + (long)p * Ee + lane * 8);
    s16x8 al = *(const s16x8*)(Alo + (long)p * Ee + lane * 8);
    float a[8];
#pragma unroll
    for (int j = 0; j < 8; ++j)
        a[j] = h2f((unsigned short)ah[j]) + h2f((unsigned short)al[j]);

    float best = -3e38f; int bi = 0x7FFFFFFF;
    auto rescore = [&](int v) {
        const float* er = emb + (long)v * Ee + lane * 8;
        float4 b0 = *(const float4*)er;
        float4 b1 = *(const float4*)(er + 4);
        float s = 0.f;
        s = fmaf(a[0], b0.x, s); s = fmaf(a[1], b0.y, s);
        s = fmaf(a[2], b0.z, s); s = fmaf(a[3], b0.w, s);
        s = fmaf(a[4], b1.x, s); s = fmaf(a[5], b1.y, s);
        s = fmaf(a[6], b1.z, s); s = fmaf(a[7], b1.w, s);
#pragma unroll
        for (int off = 1; off < 64; off <<= 1) s += __shfl_xor(s, off);
        s *= en_inv[v];
        if (s > best || (s == best && v < bi)) { best = s; bi = v; }
    };
    while (mw) {
        int b = __ffsll(mw) - 1; mw &= mw - 1;
        rescore(__shfl(wi, b));
    }
    while (me) {
        int b = __ffsll(me) - 1; me &= me - 1;
        rescore(__shfl(ei, b));
    }
    if (lane == 0) { tok_i[p] = bi; tok_f[p] = (float)bi; }
}

// ---------------- finalize: z_q gather + straight-through blend ----------------

__global__ void k_final(const float* __restrict__ z, const float* __restrict__ emb,
                        const int* __restrict__ tok, const float* __restrict__ inv_zn,
                        const float* __restrict__ en_inv, const float* __restrict__ en_norm,
                        float* __restrict__ zq, float* __restrict__ dec) {
    long gid = (long)blockIdx.x * 256 + threadIdx.x;   // 0..8388607
    int hw = (int)(gid & 1023);
    int b  = (int)(gid >> 19);
    int p  = (b << 10) | hw;
    int e  = (int)((gid >> 10) & 511);
    int tk = tok[p];
    float zqv = emb[(long)tk * Ee + e];
    float nq  = en_norm[tk];
    float nzq = zqv * en_inv[tk];
    float zv  = z[gid];
    float nz  = zv * inv_zn[p];
    zq[gid]  = zqv;
    dec[gid] = (nz + (nzq - nz)) * nq;
}

// ---------------- launch ----------------

extern "C" void kernel_launch(void* const* d_in, const int* in_sizes, int n_in,
                              void* d_out, int out_size, void* d_ws, size_t ws_size,
                              hipStream_t stream) {
    const float* x     = (const float*)d_in[0];
    const float* w_pre = (const float*)d_in[1];
    const float* b_pre = (const float*)d_in[2];
    const float* emb   = (const float*)d_in[3];

    float* out  = (float*)d_out;
    float* z    = out + O_Z;
    float* zq   = out + O_ZQ;
    float* dec  = out + O_DEC;
    float* tokf = out + O_TOK;

    // zq region (32MB): Ahi | Alo  fp16 [16384][512] each (dead until k_final)
    unsigned short* Ahi = (unsigned short*)zq;
    unsigned short* Alo = Ahi + (long)Mm * Ee;
    // dec region (8M floats): Bhi(2M) | part_v(1M) | part_i(1M) | extras(2M) | cnt | sumsq
    unsigned short* Bhi = (unsigned short*)dec;
    float*  part_v = dec + 2 * 1024 * 1024;
    int*    part_i = (int*)(dec + 3 * 1024 * 1024);
    float2* extras = (float2*)(dec + 4 * 1024 * 1024);
    int*    cnt    = (int*)(dec + 6 * 1024 * 1024);
    float*  sumsq_part = dec + 6 * 1024 * 1024 + 32768;   // 16384*4 floats

    float* ws      = (float*)d_ws;
    float* wT      = ws;                // 131072
    float* en_inv  = wT + 131072;       // 8192
    float* en_norm = en_inv + 8192;     // 8192
    float* inv_zn  = en_norm + 8192;    // 16384
    int*   tok_i   = (int*)(inv_zn + 16384); // 16384
    float* norm    = (float*)(tok_i + 16384); // 16384

    k_prep<<<2048, 256, 0, stream>>>(w_pre, wT, emb, en_inv, en_norm, Bhi, cnt);
    dim3 g1(Mm / 128, Ee / 128);
    k_gemm1<<<g1, 256, 0, stream>>>(x, wT, b_pre, z, Ahi, Alo, sumsq_part);
    k_norm<<<Mm / 256, 256, 0, stream>>>(sumsq_part, norm, inv_zn);
    k_sims<<<8192, 256, 0, stream>>>(Ahi, Bhi, norm, part_v, part_i, extras, cnt);
    k_pick<<<Mm / 4, 256, 0, stream>>>(part_v, part_i, extras, cnt, Ahi, Alo, emb,
                                       en_inv, norm, tok_i, tokf);
    k_final<<<(int)(8388608 / 256), 256, 0, stream>>>(z, emb, tok_i, inv_zn, en_inv, en_norm, zq, dec);
}

// Round 12
// 420.692 us; speedup vs baseline: 2.5690x; 1.0520x over previous
//
#include <hip/hip_runtime.h>
#include <math.h>

#define EPSF 1e-8f
#define MARGIN 4e-3f

constexpr int Bn = 16, Cc = 256, HW = 1024, Ee = 512, Vv = 8192;
constexpr int Mm = Bn * HW; // 16384 pixels

// d_out float offsets: z | z_q | decoder_input | tokens(float)
constexpr long O_Z   = 0;
constexpr long O_ZQ  = 8388608;
constexpr long O_DEC = 16777216;
constexpr long O_TOK = 25165824;

typedef __attribute__((ext_vector_type(8))) short s16x8;
typedef __attribute__((ext_vector_type(4))) short s16x4;
typedef __attribute__((ext_vector_type(8))) _Float16 f16x8;
typedef __attribute__((ext_vector_type(4))) float f32x4;

__device__ __forceinline__ unsigned short f2h(float x) {
    _Float16 h = (_Float16)x;
    return __builtin_bit_cast(unsigned short, h);
}
__device__ __forceinline__ float h2f(unsigned short b) {
    return (float)__builtin_bit_cast(_Float16, b);
}

// ---------------- k_prep: wT transpose + embedding norms/fp16 B + cnt zero ----------------

__global__ void k_prep(const float* __restrict__ w, float* __restrict__ wT,
                       const float* __restrict__ emb, float* __restrict__ en_inv,
                       float* __restrict__ en_norm, unsigned short* __restrict__ Bhi,
                       int* __restrict__ cnt) {
    int b = blockIdx.x, t = threadIdx.x;
    int v = b * 4 + (t >> 6);
    int lane = t & 63;
    const float* row = emb + (long)v * Ee + lane * 8;
    float4 d0 = *(const float4*)row;
    float4 d1 = *(const float4*)(row + 4);
    float s = 0.f;
    s = fmaf(d0.x, d0.x, s); s = fmaf(d0.y, d0.y, s);
    s = fmaf(d0.z, d0.z, s); s = fmaf(d0.w, d0.w, s);
    s = fmaf(d1.x, d1.x, s); s = fmaf(d1.y, d1.y, s);
    s = fmaf(d1.z, d1.z, s); s = fmaf(d1.w, d1.w, s);
#pragma unroll
    for (int off = 32; off; off >>= 1) s += __shfl_xor(s, off);
    float n = sqrtf(s);
    float inv = 1.0f / (EPSF + n);
    if (lane == 0) { en_norm[v] = EPSF + n; en_inv[v] = inv; }
    s16x8 h;
    h[0] = (short)f2h(d0.x * inv); h[1] = (short)f2h(d0.y * inv);
    h[2] = (short)f2h(d0.z * inv); h[3] = (short)f2h(d0.w * inv);
    h[4] = (short)f2h(d1.x * inv); h[5] = (short)f2h(d1.y * inv);
    h[6] = (short)f2h(d1.z * inv); h[7] = (short)f2h(d1.w * inv);
    *(s16x8*)(Bhi + (long)v * Ee + lane * 8) = h;
    if (b < 512) {
        int gid = b * 256 + t;
        int c = gid >> 9, e = gid & 511;
        wT[gid] = w[e * Cc + c];
    } else if (b < 576) {
        cnt[(b - 512) * 256 + t] = 0;
    }
}

// ---------------- GEMM1 (128x128 tile): z + per-pixel sumsq partials ----------------
// grid (128, 4): x re-read 4x (L3-hot); 8x8 micro-tile (64 FMA per 4 ds_read_b128).

__global__ __launch_bounds__(256) void k_gemm1(const float* __restrict__ x,
                                               const float* __restrict__ wT,
                                               const float* __restrict__ bias,
                                               float* __restrict__ z,
                                               float* __restrict__ sumsq_part) {
    __shared__ float As[32][128];   // x tile  [c][p]  16KB
    __shared__ float Bs[32][128];   // wT tile [c][e]  16KB
    int m0 = blockIdx.x * 128;                // pixel tile
    int b = m0 >> 10, hw0 = m0 & 1023;
    int e0 = blockIdx.y * 128;
    int t = threadIdx.x;
    int mi = t >> 4, ni = t & 15;             // 8 pixels x 8 e per thread
    float acc[8][8] = {};
    for (int c0 = 0; c0 < Cc; c0 += 32) {
#pragma unroll
        for (int q = 0; q < 4; ++q) {
            int f = t + 256 * q;              // 0..1023
            int kk = f >> 5, p4 = (f & 31) * 4;
            *(float4*)&As[kk][p4] = *(const float4*)(x + ((long)(b * Cc + c0 + kk)) * HW + hw0 + p4);
            *(float4*)&Bs[kk][p4] = *(const float4*)(wT + (long)(c0 + kk) * Ee + e0 + p4);
        }
        __syncthreads();
#pragma unroll
        for (int kk = 0; kk < 32; ++kk) {
            float av[8], bv[8];
            *(float4*)&av[0] = *(float4*)&As[kk][mi * 8];
            *(float4*)&av[4] = *(float4*)&As[kk][mi * 8 + 4];
            *(float4*)&bv[0] = *(float4*)&Bs[kk][ni * 8];
            *(float4*)&bv[4] = *(float4*)&Bs[kk][ni * 8 + 4];
#pragma unroll
            for (int r = 0; r < 8; ++r)
#pragma unroll
                for (int c = 0; c < 8; ++c) acc[r][c] = fmaf(av[r], bv[c], acc[r][c]);
        }
        __syncthreads();
    }
    float ov[8][8];
#pragma unroll
    for (int c = 0; c < 8; ++c) {
        int e = e0 + ni * 8 + c;
        float be = bias[e];
#pragma unroll
        for (int r = 0; r < 8; ++r) ov[r][c] = acc[r][c] + be;
        float4 o0 = make_float4(ov[0][c], ov[1][c], ov[2][c], ov[3][c]);
        float4 o1 = make_float4(ov[4][c], ov[5][c], ov[6][c], ov[7][c]);
        float* zp = z + ((long)(b * Ee + e)) * HW + hw0 + mi * 8;
        *(float4*)zp = o0;
        *(float4*)(zp + 4) = o1;
    }
    float sq[8];
#pragma unroll
    for (int r = 0; r < 8; ++r) {
        float s = 0.f;
#pragma unroll
        for (int c = 0; c < 8; ++c) s = fmaf(ov[r][c], ov[r][c], s);
        sq[r] = s;
    }
#pragma unroll
    for (int r = 0; r < 8; ++r)
#pragma unroll
        for (int off = 1; off < 16; off <<= 1) sq[r] += __shfl_xor(sq[r], off);
    if (ni == 0) {
#pragma unroll
        for (int r = 0; r < 8; ++r)
            sumsq_part[(long)(m0 + mi * 8 + r) * 4 + blockIdx.y] = sq[r];
    }
}

// ---------------- A split (R7 form, 4 partials): zn -> normalized A_hi/A_lo fp16 ----------------

__global__ void k_Asplit(const float* __restrict__ z, const float* __restrict__ sumsq_part,
                         unsigned short* __restrict__ Ahi, unsigned short* __restrict__ Alo,
                         float* __restrict__ inv_zn) {
    __shared__ float tile[64][65];
    __shared__ float inv_s[64];
    int p0 = (blockIdx.x >> 3) * 64;   // 256 p-tiles
    int e0 = (blockIdx.x & 7) * 64;    // 8 e-tiles
    int b = p0 >> 10, hw0 = p0 & 1023;
    int t = threadIdx.x;
    if (t < 64) {
        const float* sp = sumsq_part + (long)(p0 + t) * 4;
        float s = (sp[0] + sp[1]) + (sp[2] + sp[3]);
        float inv = 1.0f / (EPSF + sqrtf(s));
        inv_s[t] = inv;
        if ((blockIdx.x & 7) == 0) inv_zn[p0 + t] = inv;
    }
#pragma unroll
    for (int q = 0; q < 4; ++q) {
        int f = t + 256 * q;
        int e_l = f >> 4, p4 = (f & 15) * 4;
        float4 d = *(const float4*)(z + ((long)(b * Ee + e0 + e_l)) * HW + hw0 + p4);
        tile[e_l][p4 + 0] = d.x; tile[e_l][p4 + 1] = d.y;
        tile[e_l][p4 + 2] = d.z; tile[e_l][p4 + 3] = d.w;
    }
    __syncthreads();
#pragma unroll
    for (int q = 0; q < 4; ++q) {
        int f = t + 256 * q;
        int p_l = f >> 4, e4 = (f & 15) * 4;
        float inv = inv_s[p_l];
        s16x4 h, lo;
#pragma unroll
        for (int j = 0; j < 4; ++j) {
            float xv = tile[e4 + j][p_l] * inv;
            unsigned short hh = f2h(xv);
            h[j]  = (short)hh;
            lo[j] = (short)f2h(xv - h2f(hh));
        }
        long off = (long)(p0 + p_l) * Ee + e0 + e4;
        *(s16x4*)(Ahi + off) = h;
        *(s16x4*)(Alo + off) = lo;
    }
}

// ---------------- fp16 MFMA sims: R7 structure VERBATIM (235us, measured twice) ----------------
// 8192 blocks (128 m x 64 v), 256 thr = 4 waves (2x2), 128x128 tile, K=512.
// Single 32KB LDS buffer, global_load_lds staging, 2 barriers/K-step.
// Grid mapping is load-bearing (R10 lesson): 16 co-resident m-tiles/XCD share
// one B-tile -> FETCH 42MB. Normalized A -> constant MARGIN (no norm loads).

__global__ __launch_bounds__(256, 4) void k_sims(const unsigned short* __restrict__ Ahi,
                                                 const unsigned short* __restrict__ Bhi,
                                                 float* __restrict__ part_v,
                                                 int* __restrict__ part_i,
                                                 float2* __restrict__ extras,
                                                 int* __restrict__ cnt) {
    __shared__ short As[8192];   // [row*64 + slot*8 + e]  16KB
    __shared__ short Bs[8192];
    __shared__ float red_v[2][2][64];
    __shared__ int   red_i[2][2][64];
    __shared__ float red_m[2][64];
    __shared__ int   red_wi[2][64];

    int t = threadIdx.x;
    int wg = blockIdx.x;
    int xcd = wg & 7, r = wg >> 3;
    int bx = xcd * 16 + (r & 15);     // 0..127  (m-tile), XCD-chunked
    int by = r >> 4;                  // 0..63   (v-tile)
    long m0 = (long)bx * 128, n0 = (long)by * 128;

    int wid = t >> 6, l = t & 63;
    int wr = wid >> 1, wc = wid & 1;
    int l15 = l & 15, lg = l >> 4;

    auto stage = [&](const unsigned short* gbase, short* region, long row0, int k0) {
#pragma unroll
        for (int j = 0; j < 4; ++j) {
            int i = j * 256 + t;               // slot 0..1023
            int rr = i >> 3, s = i & 7;
            int sp = s ^ (rr & 7);             // pre-swizzled global source
            const unsigned short* gp = gbase + (row0 + rr) * Ee + k0 + sp * 8;
            short* lp = region + (long)(j * 256 + (t & ~63)) * 8;  // wave-uniform
            __builtin_amdgcn_global_load_lds(
                (const __attribute__((address_space(1))) unsigned int*)gp,
                (__attribute__((address_space(3))) unsigned int*)lp, 16, 0, 0);
        }
    };

    f32x4 acc[4][4];
#pragma unroll
    for (int i = 0; i < 4; ++i)
#pragma unroll
        for (int j = 0; j < 4; ++j) acc[i][j] = (f32x4){0.f, 0.f, 0.f, 0.f};

    stage(Ahi, As, m0, 0);
    stage(Bhi, Bs, n0, 0);

    for (int kt = 0; kt < 8; ++kt) {
        __syncthreads();   // vmcnt(0)+barrier: tile kt landed for all waves
        s16x8 af[4][2], bf[4][2];
#pragma unroll
        for (int mt = 0; mt < 4; ++mt)
#pragma unroll
            for (int kk = 0; kk < 2; ++kk) {
                int row = wr * 64 + mt * 16 + l15;
                int g = kk * 4 + lg;
                af[mt][kk] = *(const s16x8*)&As[row * 64 + ((g ^ (row & 7)) * 8)];
                int nrow = wc * 64 + mt * 16 + l15;
                bf[mt][kk] = *(const s16x8*)&Bs[nrow * 64 + ((g ^ (nrow & 7)) * 8)];
            }
        __syncthreads();   // all waves' reads complete
        if (kt < 7) {
            stage(Ahi, As, m0, (kt + 1) * 64);   // DMAs fly under the MFMAs
            stage(Bhi, Bs, n0, (kt + 1) * 64);
        }
#pragma unroll
        for (int kk = 0; kk < 2; ++kk)
#pragma unroll
            for (int mt = 0; mt < 4; ++mt)
#pragma unroll
                for (int nt = 0; nt < 4; ++nt)
                    acc[mt][nt] = __builtin_amdgcn_mfma_f32_16x16x32_f16(
                        __builtin_bit_cast(f16x8, af[mt][kk]),
                        __builtin_bit_cast(f16x8, bf[nt][kk]), acc[mt][nt], 0, 0, 0);
    }

    // ---- winner epilogue (C/D: col = l&15, row = (l>>4)*4 + reg) ----
#pragma unroll
    for (int mt = 0; mt < 4; ++mt)
#pragma unroll
        for (int rg = 0; rg < 4; ++rg) {
            float best = -3e38f; int bi = 0x7FFFFFFF;
#pragma unroll
            for (int nt = 0; nt < 4; ++nt) {
                float val = acc[mt][nt][rg];
                int idx = (int)n0 + wc * 64 + nt * 16 + l15;
                if (val > best) { best = val; bi = idx; }
            }
#pragma unroll
            for (int off = 1; off < 16; off <<= 1) {
                float ov = __shfl_xor(best, off);
                int oi = __shfl_xor(bi, off);
                if (ov > best || (ov == best && oi < bi)) { best = ov; bi = oi; }
            }
            if (l15 == 0) {
                int rloc = mt * 16 + lg * 4 + rg;
                red_v[wr][wc][rloc] = best;
                red_i[wr][wc][rloc] = bi;
            }
        }
    __syncthreads();
    if (t < 128) {
        int wr_ = t >> 6, rloc = t & 63;
        float va = red_v[wr_][0][rloc]; int ia = red_i[wr_][0][rloc];
        float vb = red_v[wr_][1][rloc]; int ib = red_i[wr_][1][rloc];
        if (vb > va || (vb == va && ib < ia)) { va = vb; ia = ib; }
        long m = m0 + wr_ * 64 + rloc;
        part_v[m * 64 + by] = va;
        part_i[m * 64 + by] = ia;
        red_m[wr_][rloc] = va;
        red_wi[wr_][rloc] = ia;
    }
    __syncthreads();
    // ---- extras: every non-winner col within MARGIN of the stripe max ----
#pragma unroll
    for (int mt = 0; mt < 4; ++mt)
#pragma unroll
        for (int rg = 0; rg < 4; ++rg) {
            int rloc = mt * 16 + lg * 4 + rg;
            float bm = red_m[wr][rloc];
            int wi_ = red_wi[wr][rloc];
            long p = m0 + wr * 64 + rloc;
            float thr = bm - MARGIN;
#pragma unroll
            for (int nt = 0; nt < 4; ++nt) {
                float val = acc[mt][nt][rg];
                int idx = (int)n0 + wc * 64 + nt * 16 + l15;
                if (val >= thr && idx != wi_) {
                    int slot = atomicAdd(&cnt[p], 1);
                    if (slot < 64) extras[p * 64 + slot] = make_float2(val, __int_as_float(idx));
                }
            }
        }
}

// ---------------- k_pick: global m1, candidate set, exact f32 rescore (R7 form) ----------------

__global__ __launch_bounds__(256) void k_pick(const float* __restrict__ part_v,
                                              const int* __restrict__ part_i,
                                              const float2* __restrict__ extras,
                                              const int* __restrict__ cnt,
                                              const unsigned short* __restrict__ Ahi,
                                              const unsigned short* __restrict__ Alo,
                                              const float* __restrict__ emb,
                                              const float* __restrict__ en_inv,
                                              int* __restrict__ tok_i,
                                              float* __restrict__ tok_f) {
    int p = blockIdx.x * 4 + (threadIdx.x >> 6);
    int lane = threadIdx.x & 63;
    float wv = part_v[(long)p * 64 + lane];
    int wi = part_i[(long)p * 64 + lane];
    float m1 = wv;
#pragma unroll
    for (int off = 1; off < 64; off <<= 1) {
        float ov = __shfl_xor(m1, off);
        if (ov > m1) m1 = ov;
    }
    float thr = m1 - MARGIN;
    int n = cnt[p]; if (n > 64) n = 64;
    float ev = -3e38f; int ei = 0;
    if (lane < n) {
        float2 e2 = extras[(long)p * 64 + lane];
        ev = e2.x; ei = __float_as_int(e2.y);
    }
    unsigned long long mw = __ballot(wv >= thr);
    unsigned long long me = __ballot(ev >= thr);
    // preload this pixel's zn row slice (reconstructed f32)
    s16x8 ah = *(const s16x8*)(Ahi + (long)p * Ee + lane * 8);
    s16x8 al = *(const s16x8*)(Alo + (long)p * Ee + lane * 8);
    float a[8];
#pragma unroll
    for (int j = 0; j < 8; ++j)
        a[j] = h2f((unsigned short)ah[j]) + h2f((unsigned short)al[j]);

    float best = -3e38f; int bi = 0x7FFFFFFF;
    auto rescore = [&](int v) {
        const float* er = emb + (long)v * Ee + lane * 8;
        float4 b0 = *(const float4*)er;
        float4 b1 = *(const float4*)(er + 4);
        float s = 0.f;
        s = fmaf(a[0], b0.x, s); s = fmaf(a[1], b0.y, s);
        s = fmaf(a[2], b0.z, s); s = fmaf(a[3], b0.w, s);
        s = fmaf(a[4], b1.x, s); s = fmaf(a[5], b1.y, s);
        s = fmaf(a[6], b1.z, s); s = fmaf(a[7], b1.w, s);
#pragma unroll
        for (int off = 1; off < 64; off <<= 1) s += __shfl_xor(s, off);
        s *= en_inv[v];
        if (s > best || (s == best && v < bi)) { best = s; bi = v; }
    };
    while (mw) {
        int b = __ffsll(mw) - 1; mw &= mw - 1;
        rescore(__shfl(wi, b));
    }
    while (me) {
        int b = __ffsll(me) - 1; me &= me - 1;
        rescore(__shfl(ei, b));
    }
    if (lane == 0) { tok_i[p] = bi; tok_f[p] = (float)bi; }
}

// ---------------- finalize: z_q gather + straight-through blend (float4 over hw) ----------------

__global__ void k_final(const float* __restrict__ z, const float* __restrict__ emb,
                        const int* __restrict__ tok, const float* __restrict__ inv_zn,
                        const float* __restrict__ en_inv, const float* __restrict__ en_norm,
                        float* __restrict__ zq, float* __restrict__ dec) {
    long u = (long)blockIdx.x * 256 + threadIdx.x;   // 0..2097151 (4 elems each)
    int hw4 = (int)(u & 255) * 4;
    int e   = (int)((u >> 8) & 511);
    int b   = (int)(u >> 17);
    long gid = ((long)(b * Ee + e)) * HW + hw4;
    int pb = (b << 10) | hw4;
    float4 zv = *(const float4*)(z + gid);
    float zvv[4] = {zv.x, zv.y, zv.z, zv.w};
    float zqv[4], dcv[4];
#pragma unroll
    for (int j = 0; j < 4; ++j) {
        int p = pb + j;
        int tk = tok[p];
        float q  = emb[(long)tk * Ee + e];
        float nq  = en_norm[tk];
        float nzq = q * en_inv[tk];
        float nz  = zvv[j] * inv_zn[p];
        zqv[j] = q;
        dcv[j] = (nz + (nzq - nz)) * nq;
    }
    *(float4*)(zq + gid)  = make_float4(zqv[0], zqv[1], zqv[2], zqv[3]);
    *(float4*)(dec + gid) = make_float4(dcv[0], dcv[1], dcv[2], dcv[3]);
}

// ---------------- launch ----------------

extern "C" void kernel_launch(void* const* d_in, const int* in_sizes, int n_in,
                              void* d_out, int out_size, void* d_ws, size_t ws_size,
                              hipStream_t stream) {
    const float* x     = (const float*)d_in[0];
    const float* w_pre = (const float*)d_in[1];
    const float* b_pre = (const float*)d_in[2];
    const float* emb   = (const float*)d_in[3];

    float* out  = (float*)d_out;
    float* z    = out + O_Z;
    float* zq   = out + O_ZQ;
    float* dec  = out + O_DEC;
    float* tokf = out + O_TOK;

    // zq region (32MB): Ahi | Alo  fp16 [16384][512] each (dead until k_final)
    unsigned short* Ahi = (unsigned short*)zq;
    unsigned short* Alo = Ahi + (long)Mm * Ee;
    // dec region (8M floats): Bhi(2M) | part_v(1M) | part_i(1M) | extras(2M) | cnt | sumsq
    unsigned short* Bhi = (unsigned short*)dec;
    float*  part_v = dec + 2 * 1024 * 1024;
    int*    part_i = (int*)(dec + 3 * 1024 * 1024);
    float2* extras = (float2*)(dec + 4 * 1024 * 1024);
    int*    cnt    = (int*)(dec + 6 * 1024 * 1024);
    float*  sumsq_part = dec + 6 * 1024 * 1024 + 32768;   // 16384*4 floats

    float* ws      = (float*)d_ws;
    float* wT      = ws;                // 131072
    float* en_inv  = wT + 131072;       // 8192
    float* en_norm = en_inv + 8192;     // 8192
    float* inv_zn  = en_norm + 8192;    // 16384
    int*   tok_i   = (int*)(inv_zn + 16384); // 16384

    k_prep<<<2048, 256, 0, stream>>>(w_pre, wT, emb, en_inv, en_norm, Bhi, cnt);
    dim3 g1(Mm / 128, Ee / 128);
    k_gemm1<<<g1, 256, 0, stream>>>(x, wT, b_pre, z, sumsq_part);
    k_Asplit<<<2048, 256, 0, stream>>>(z, sumsq_part, Ahi, Alo, inv_zn);
    k_sims<<<8192, 256, 0, stream>>>(Ahi, Bhi, part_v, part_i, extras, cnt);
    k_pick<<<Mm / 4, 256, 0, stream>>>(part_v, part_i, extras, cnt, Ahi, Alo, emb,
                                       en_inv, tok_i, tokf);
    k_final<<<8192, 256, 0, stream>>>(z, emb, tok_i, inv_zn, en_inv, en_norm, zq, dec);
}

// Round 13
// 417.023 us; speedup vs baseline: 2.5916x; 1.0088x over previous
//
#include <hip/hip_runtime.h>
#include <math.h>

#define EPSF 1e-8f
#define MARGIN 4e-3f

constexpr int Bn = 16, Cc = 256, HW = 1024, Ee = 512, Vv = 8192;
constexpr int Mm = Bn * HW; // 16384 pixels

// d_out float offsets: z | z_q | decoder_input | tokens(float)
constexpr long O_Z   = 0;
constexpr long O_ZQ  = 8388608;
constexpr long O_DEC = 16777216;
constexpr long O_TOK = 25165824;

typedef __attribute__((ext_vector_type(8))) short s16x8;
typedef __attribute__((ext_vector_type(4))) short s16x4;
typedef __attribute__((ext_vector_type(8))) _Float16 f16x8;
typedef __attribute__((ext_vector_type(4))) float f32x4;

__device__ __forceinline__ unsigned short f2h(float x) {
    _Float16 h = (_Float16)x;
    return __builtin_bit_cast(unsigned short, h);
}
__device__ __forceinline__ float h2f(unsigned short b) {
    return (float)__builtin_bit_cast(_Float16, b);
}

// ---------------- k_prep: wT transpose + embedding norms/fp16 B + cnt zero ----------------

__global__ void k_prep(const float* __restrict__ w, float* __restrict__ wT,
                       const float* __restrict__ emb, float* __restrict__ en_inv,
                       float* __restrict__ en_norm, unsigned short* __restrict__ Bhi,
                       int* __restrict__ cnt) {
    int b = blockIdx.x, t = threadIdx.x;
    int v = b * 4 + (t >> 6);
    int lane = t & 63;
    const float* row = emb + (long)v * Ee + lane * 8;
    float4 d0 = *(const float4*)row;
    float4 d1 = *(const float4*)(row + 4);
    float s = 0.f;
    s = fmaf(d0.x, d0.x, s); s = fmaf(d0.y, d0.y, s);
    s = fmaf(d0.z, d0.z, s); s = fmaf(d0.w, d0.w, s);
    s = fmaf(d1.x, d1.x, s); s = fmaf(d1.y, d1.y, s);
    s = fmaf(d1.z, d1.z, s); s = fmaf(d1.w, d1.w, s);
#pragma unroll
    for (int off = 32; off; off >>= 1) s += __shfl_xor(s, off);
    float n = sqrtf(s);
    float inv = 1.0f / (EPSF + n);
    if (lane == 0) { en_norm[v] = EPSF + n; en_inv[v] = inv; }
    s16x8 h;
    h[0] = (short)f2h(d0.x * inv); h[1] = (short)f2h(d0.y * inv);
    h[2] = (short)f2h(d0.z * inv); h[3] = (short)f2h(d0.w * inv);
    h[4] = (short)f2h(d1.x * inv); h[5] = (short)f2h(d1.y * inv);
    h[6] = (short)f2h(d1.z * inv); h[7] = (short)f2h(d1.w * inv);
    *(s16x8*)(Bhi + (long)v * Ee + lane * 8) = h;
    if (b < 512) {
        int gid = b * 256 + t;
        int c = gid >> 9, e = gid & 511;
        wT[gid] = w[e * Cc + c];
    } else if (b < 576) {
        cnt[(b - 512) * 256 + t] = 0;
    }
}

// ---------------- GEMM1 (128x128): z + fp16 hi/lo of UNNORMALIZED z + sumsq partials ----------------
// (R11-verified fused form.) grid (128, 4); 8x8 micro-tile.

__global__ __launch_bounds__(256) void k_gemm1(const float* __restrict__ x,
                                               const float* __restrict__ wT,
                                               const float* __restrict__ bias,
                                               float* __restrict__ z,
                                               unsigned short* __restrict__ Ahi,
                                               unsigned short* __restrict__ Alo,
                                               float* __restrict__ sumsq_part) {
    __shared__ float As[32][128];   // x tile  [c][p]  16KB
    __shared__ float Bs[32][128];   // wT tile [c][e]  16KB
    int m0 = blockIdx.x * 128;                // pixel tile
    int b = m0 >> 10, hw0 = m0 & 1023;
    int e0 = blockIdx.y * 128;
    int t = threadIdx.x;
    int mi = t >> 4, ni = t & 15;             // 8 pixels x 8 e per thread
    float acc[8][8] = {};
    for (int c0 = 0; c0 < Cc; c0 += 32) {
#pragma unroll
        for (int q = 0; q < 4; ++q) {
            int f = t + 256 * q;              // 0..1023
            int kk = f >> 5, p4 = (f & 31) * 4;
            *(float4*)&As[kk][p4] = *(const float4*)(x + ((long)(b * Cc + c0 + kk)) * HW + hw0 + p4);
            *(float4*)&Bs[kk][p4] = *(const float4*)(wT + (long)(c0 + kk) * Ee + e0 + p4);
        }
        __syncthreads();
#pragma unroll
        for (int kk = 0; kk < 32; ++kk) {
            float av[8], bv[8];
            *(float4*)&av[0] = *(float4*)&As[kk][mi * 8];
            *(float4*)&av[4] = *(float4*)&As[kk][mi * 8 + 4];
            *(float4*)&bv[0] = *(float4*)&Bs[kk][ni * 8];
            *(float4*)&bv[4] = *(float4*)&Bs[kk][ni * 8 + 4];
#pragma unroll
            for (int r = 0; r < 8; ++r)
#pragma unroll
                for (int c = 0; c < 8; ++c) acc[r][c] = fmaf(av[r], bv[c], acc[r][c]);
        }
        __syncthreads();
    }
    float ov[8][8];
#pragma unroll
    for (int c = 0; c < 8; ++c) {
        int e = e0 + ni * 8 + c;
        float be = bias[e];
#pragma unroll
        for (int r = 0; r < 8; ++r) ov[r][c] = acc[r][c] + be;
        float4 o0 = make_float4(ov[0][c], ov[1][c], ov[2][c], ov[3][c]);
        float4 o1 = make_float4(ov[4][c], ov[5][c], ov[6][c], ov[7][c]);
        float* zp = z + ((long)(b * Ee + e)) * HW + hw0 + mi * 8;
        *(float4*)zp = o0;
        *(float4*)(zp + 4) = o1;
    }
    float sq[8];
#pragma unroll
    for (int r = 0; r < 8; ++r) {
        s16x8 h, lo;
        float s = 0.f;
#pragma unroll
        for (int c = 0; c < 8; ++c) {
            unsigned short hh = f2h(ov[r][c]);
            h[c]  = (short)hh;
            lo[c] = (short)f2h(ov[r][c] - h2f(hh));
            s = fmaf(ov[r][c], ov[r][c], s);
        }
        sq[r] = s;
        long off = (long)(m0 + mi * 8 + r) * Ee + e0 + ni * 8;
        *(s16x8*)(Ahi + off) = h;
        *(s16x8*)(Alo + off) = lo;
    }
#pragma unroll
    for (int r = 0; r < 8; ++r)
#pragma unroll
        for (int off = 1; off < 16; off <<= 1) sq[r] += __shfl_xor(sq[r], off);
    if (ni == 0) {
#pragma unroll
        for (int r = 0; r < 8; ++r)
            sumsq_part[(long)(m0 + mi * 8 + r) * 4 + blockIdx.y] = sq[r];
    }
}

// ---------------- k_norm: fold 4 sumsq partials -> norm / inv_zn ----------------

__global__ void k_norm(const float* __restrict__ sumsq_part, float* __restrict__ norm,
                       float* __restrict__ inv_zn) {
    int p = blockIdx.x * 256 + threadIdx.x;
    const float* sp = sumsq_part + (long)p * 4;
    float s = (sp[0] + sp[1]) + (sp[2] + sp[3]);
    float nv = EPSF + sqrtf(s);
    norm[p] = nv;
    inv_zn[p] = 1.0f / nv;
}

// ---------------- fp16 MFMA sims: R12 core + LDS-staged norms (no scattered loads) ----------------
// 8192 blocks (128 m x 64 v), 256 thr = 4 waves (2x2), 128x128 tile, K=512.
// Single 32KB LDS buffer, global_load_lds staging, 2 barriers/K-step.
// Grid mapping load-bearing (R10 lesson). A side = UNNORMALIZED z fp16
// (argmax scale-invariant; R10/R11-verified); margin = MARGIN * norm_s[row]
// with norm_s staged ONCE per block via one coalesced 512B read (fixes
// R11's 16-scattered-load epilogue stall).

__global__ __launch_bounds__(256, 4) void k_sims(const unsigned short* __restrict__ Ahi,
                                                 const unsigned short* __restrict__ Bhi,
                                                 const float* __restrict__ norm,
                                                 float* __restrict__ part_v,
                                                 int* __restrict__ part_i,
                                                 float2* __restrict__ extras,
                                                 int* __restrict__ cnt) {
    __shared__ short As[8192];   // [row*64 + slot*8 + e]  16KB
    __shared__ short Bs[8192];
    __shared__ float red_v[2][2][64];
    __shared__ int   red_i[2][2][64];
    __shared__ float red_m[2][64];
    __shared__ int   red_wi[2][64];
    __shared__ float norm_s[128];

    int t = threadIdx.x;
    int wg = blockIdx.x;
    int xcd = wg & 7, r = wg >> 3;
    int bx = xcd * 16 + (r & 15);     // 0..127  (m-tile), XCD-chunked
    int by = r >> 4;                  // 0..63   (v-tile)
    long m0 = (long)bx * 128, n0 = (long)by * 128;

    int wid = t >> 6, l = t & 63;
    int wr = wid >> 1, wc = wid & 1;
    int l15 = l & 15, lg = l >> 4;

    auto stage = [&](const unsigned short* gbase, short* region, long row0, int k0) {
#pragma unroll
        for (int j = 0; j < 4; ++j) {
            int i = j * 256 + t;               // slot 0..1023
            int rr = i >> 3, s = i & 7;
            int sp = s ^ (rr & 7);             // pre-swizzled global source
            const unsigned short* gp = gbase + (row0 + rr) * Ee + k0 + sp * 8;
            short* lp = region + (long)(j * 256 + (t & ~63)) * 8;  // wave-uniform
            __builtin_amdgcn_global_load_lds(
                (const __attribute__((address_space(1))) unsigned int*)gp,
                (__attribute__((address_space(3))) unsigned int*)lp, 16, 0, 0);
        }
    };

    f32x4 acc[4][4];
#pragma unroll
    for (int i = 0; i < 4; ++i)
#pragma unroll
        for (int j = 0; j < 4; ++j) acc[i][j] = (f32x4){0.f, 0.f, 0.f, 0.f};

    if (t < 128) norm_s[t] = norm[m0 + t];   // one coalesced 512B read

    stage(Ahi, As, m0, 0);
    stage(Bhi, Bs, n0, 0);

    for (int kt = 0; kt < 8; ++kt) {
        __syncthreads();   // vmcnt(0)+barrier: tile kt landed for all waves
        s16x8 af[4][2], bf[4][2];
#pragma unroll
        for (int mt = 0; mt < 4; ++mt)
#pragma unroll
            for (int kk = 0; kk < 2; ++kk) {
                int row = wr * 64 + mt * 16 + l15;
                int g = kk * 4 + lg;
                af[mt][kk] = *(const s16x8*)&As[row * 64 + ((g ^ (row & 7)) * 8)];
                int nrow = wc * 64 + mt * 16 + l15;
                bf[mt][kk] = *(const s16x8*)&Bs[nrow * 64 + ((g ^ (nrow & 7)) * 8)];
            }
        __syncthreads();   // all waves' reads complete
        if (kt < 7) {
            stage(Ahi, As, m0, (kt + 1) * 64);   // DMAs fly under the MFMAs
            stage(Bhi, Bs, n0, (kt + 1) * 64);
        }
#pragma unroll
        for (int kk = 0; kk < 2; ++kk)
#pragma unroll
            for (int mt = 0; mt < 4; ++mt)
#pragma unroll
                for (int nt = 0; nt < 4; ++nt)
                    acc[mt][nt] = __builtin_amdgcn_mfma_f32_16x16x32_f16(
                        __builtin_bit_cast(f16x8, af[mt][kk]),
                        __builtin_bit_cast(f16x8, bf[nt][kk]), acc[mt][nt], 0, 0, 0);
    }

    // ---- winner epilogue (C/D: col = l&15, row = (l>>4)*4 + reg) ----
#pragma unroll
    for (int mt = 0; mt < 4; ++mt)
#pragma unroll
        for (int rg = 0; rg < 4; ++rg) {
            float best = -3e38f; int bi = 0x7FFFFFFF;
#pragma unroll
            for (int nt = 0; nt < 4; ++nt) {
                float val = acc[mt][nt][rg];
                int idx = (int)n0 + wc * 64 + nt * 16 + l15;
                if (val > best) { best = val; bi = idx; }
            }
#pragma unroll
            for (int off = 1; off < 16; off <<= 1) {
                float ov = __shfl_xor(best, off);
                int oi = __shfl_xor(bi, off);
                if (ov > best || (ov == best && oi < bi)) { best = ov; bi = oi; }
            }
            if (l15 == 0) {
                int rloc = mt * 16 + lg * 4 + rg;
                red_v[wr][wc][rloc] = best;
                red_i[wr][wc][rloc] = bi;
            }
        }
    __syncthreads();
    if (t < 128) {
        int wr_ = t >> 6, rloc = t & 63;
        float va = red_v[wr_][0][rloc]; int ia = red_i[wr_][0][rloc];
        float vb = red_v[wr_][1][rloc]; int ib = red_i[wr_][1][rloc];
        if (vb > va || (vb == va && ib < ia)) { va = vb; ia = ib; }
        long m = m0 + wr_ * 64 + rloc;
        part_v[m * 64 + by] = va;
        part_i[m * 64 + by] = ia;
        red_m[wr_][rloc] = va;
        red_wi[wr_][rloc] = ia;
    }
    __syncthreads();
    // ---- extras: every non-winner col within MARGIN*norm of the stripe max ----
#pragma unroll
    for (int mt = 0; mt < 4; ++mt)
#pragma unroll
        for (int rg = 0; rg < 4; ++rg) {
            int rloc = mt * 16 + lg * 4 + rg;
            float bm = red_m[wr][rloc];
            int wi_ = red_wi[wr][rloc];
            int rowl = wr * 64 + rloc;
            long p = m0 + rowl;
            float thr = bm - MARGIN * norm_s[rowl];
#pragma unroll
            for (int nt = 0; nt < 4; ++nt) {
                float val = acc[mt][nt][rg];
                int idx = (int)n0 + wc * 64 + nt * 16 + l15;
                if (val >= thr && idx != wi_) {
                    int slot = atomicAdd(&cnt[p], 1);
                    if (slot < 64) extras[p * 64 + slot] = make_float2(val, __int_as_float(idx));
                }
            }
        }
}

// ---------------- k_pick: global m1, candidate set, exact f32 rescore ----------------

__global__ __launch_bounds__(256) void k_pick(const float* __restrict__ part_v,
                                              const int* __restrict__ part_i,
                                              const float2* __restrict__ extras,
                                              const int* __restrict__ cnt,
                                              const unsigned short* __restrict__ Ahi,
                                              const unsigned short* __restrict__ Alo,
                                              const float* __restrict__ emb,
                                              const float* __restrict__ en_inv,
                                              const float* __restrict__ norm,
                                              int* __restrict__ tok_i,
                                              float* __restrict__ tok_f) {
    int p = blockIdx.x * 4 + (threadIdx.x >> 6);
    int lane = threadIdx.x & 63;
    float wv = part_v[(long)p * 64 + lane];
    int wi = part_i[(long)p * 64 + lane];
    float m1 = wv;
#pragma unroll
    for (int off = 1; off < 64; off <<= 1) {
        float ov = __shfl_xor(m1, off);
        if (ov > m1) m1 = ov;
    }
    float thr = m1 - MARGIN * norm[p];
    int n = cnt[p]; if (n > 64) n = 64;
    float ev = -3e38f; int ei = 0;
    if (lane < n) {
        float2 e2 = extras[(long)p * 64 + lane];
        ev = e2.x; ei = __float_as_int(e2.y);
    }
    unsigned long long mw = __ballot(wv >= thr);
    unsigned long long me = __ballot(ev >= thr);
    // reconstruct this pixel's (unnormalized) z slice; per-pixel scale cancels
    s16x8 ah = *(const s16x8*)(Ahi + (long)p * Ee + lane * 8);
    s16x8 al = *(const s16x8*)(Alo + (long)p * Ee + lane * 8);
    float a[8];
#pragma unroll
    for (int j = 0; j < 8; ++j)
        a[j] = h2f((unsigned short)ah[j]) + h2f((unsigned short)al[j]);

    float best = -3e38f; int bi = 0x7FFFFFFF;
    auto rescore = [&](int v) {
        const float* er = emb + (long)v * Ee + lane * 8;
        float4 b0 = *(const float4*)er;
        float4 b1 = *(const float4*)(er + 4);
        float s = 0.f;
        s = fmaf(a[0], b0.x, s); s = fmaf(a[1], b0.y, s);
        s = fmaf(a[2], b0.z, s); s = fmaf(a[3], b0.w, s);
        s = fmaf(a[4], b1.x, s); s = fmaf(a[5], b1.y, s);
        s = fmaf(a[6], b1.z, s); s = fmaf(a[7], b1.w, s);
#pragma unroll
        for (int off = 1; off < 64; off <<= 1) s += __shfl_xor(s, off);
        s *= en_inv[v];
        if (s > best || (s == best && v < bi)) { best = s; bi = v; }
    };
    while (mw) {
        int b = __ffsll(mw) - 1; mw &= mw - 1;
        rescore(__shfl(wi, b));
    }
    while (me) {
        int b = __ffsll(me) - 1; me &= me - 1;
        rescore(__shfl(ei, b));
    }
    if (lane == 0) { tok_i[p] = bi; tok_f[p] = (float)bi; }
}

// ---------------- finalize: z_q gather + straight-through blend (float4 over hw) ----------------

__global__ void k_final(const float* __restrict__ z, const float* __restrict__ emb,
                        const int* __restrict__ tok, const float* __restrict__ inv_zn,
                        const float* __restrict__ en_inv, const float* __restrict__ en_norm,
                        float* __restrict__ zq, float* __restrict__ dec) {
    long u = (long)blockIdx.x * 256 + threadIdx.x;   // 0..2097151 (4 elems each)
    int hw4 = (int)(u & 255) * 4;
    int e   = (int)((u >> 8) & 511);
    int b   = (int)(u >> 17);
    long gid = ((long)(b * Ee + e)) * HW + hw4;
    int pb = (b << 10) | hw4;
    float4 zv = *(const float4*)(z + gid);
    float zvv[4] = {zv.x, zv.y, zv.z, zv.w};
    float zqv[4], dcv[4];
#pragma unroll
    for (int j = 0; j < 4; ++j) {
        int p = pb + j;
        int tk = tok[p];
        float q  = emb[(long)tk * Ee + e];
        float nq  = en_norm[tk];
        float nzq = q * en_inv[tk];
        float nz  = zvv[j] * inv_zn[p];
        zqv[j] = q;
        dcv[j] = (nz + (nzq - nz)) * nq;
    }
    *(float4*)(zq + gid)  = make_float4(zqv[0], zqv[1], zqv[2], zqv[3]);
    *(float4*)(dec + gid) = make_float4(dcv[0], dcv[1], dcv[2], dcv[3]);
}

// ---------------- launch ----------------

extern "C" void kernel_launch(void* const* d_in, const int* in_sizes, int n_in,
                              void* d_out, int out_size, void* d_ws, size_t ws_size,
                              hipStream_t stream) {
    const float* x     = (const float*)d_in[0];
    const float* w_pre = (const float*)d_in[1];
    const float* b_pre = (const float*)d_in[2];
    const float* emb   = (const float*)d_in[3];

    float* out  = (float*)d_out;
    float* z    = out + O_Z;
    float* zq   = out + O_ZQ;
    float* dec  = out + O_DEC;
    float* tokf = out + O_TOK;

    // zq region (32MB): Ahi | Alo  fp16 [16384][512] each (dead until k_final)
    unsigned short* Ahi = (unsigned short*)zq;
    unsigned short* Alo = Ahi + (long)Mm * Ee;
    // dec region (8M floats): Bhi(2M) | part_v(1M) | part_i(1M) | extras(2M) | cnt | sumsq
    unsigned short* Bhi = (unsigned short*)dec;
    float*  part_v = dec + 2 * 1024 * 1024;
    int*    part_i = (int*)(dec + 3 * 1024 * 1024);
    float2* extras = (float2*)(dec + 4 * 1024 * 1024);
    int*    cnt    = (int*)(dec + 6 * 1024 * 1024);
    float*  sumsq_part = dec + 6 * 1024 * 1024 + 32768;   // 16384*4 floats

    float* ws      = (float*)d_ws;
    float* wT      = ws;                // 131072
    float* en_inv  = wT + 131072;       // 8192
    float* en_norm = en_inv + 8192;     // 8192
    float* inv_zn  = en_norm + 8192;    // 16384
    int*   tok_i   = (int*)(inv_zn + 16384); // 16384
    float* norm    = (float*)(tok_i + 16384); // 16384

    k_prep<<<2048, 256, 0, stream>>>(w_pre, wT, emb, en_inv, en_norm, Bhi, cnt);
    dim3 g1(Mm / 128, Ee / 128);
    k_gemm1<<<g1, 256, 0, stream>>>(x, wT, b_pre, z, Ahi, Alo, sumsq_part);
    k_norm<<<Mm / 256, 256, 0, stream>>>(sumsq_part, norm, inv_zn);
    k_sims<<<8192, 256, 0, stream>>>(Ahi, Bhi, norm, part_v, part_i, extras, cnt);
    k_pick<<<Mm / 4, 256, 0, stream>>>(part_v, part_i, extras, cnt, Ahi, Alo, emb,
                                       en_inv, norm, tok_i, tokf);
    k_final<<<8192, 256, 0, stream>>>(z, emb, tok_i, inv_zn, en_inv, en_norm, zq, dec);
}